// Round 6
// baseline (81.143 us; speedup 1.0000x reference)
//
#include <hip/hip_runtime.h>

#define CUT_SIZE 224
#define SIDE 1024
#define CUTN 128
#define NSLAB 8           // 8 slabs x 128 image rows; slab s -> XCD s via bid&7
#define LDSW 1032         // floats per blended row (max needed 1024) + slack

// d_ws layout (uint32 words):
//   r_lo[NSLAB][CUTN]   @ 0      : first output row of cutout n sourced from slab s
//   P[NSLAB][CUTN+1]    @ 1024   : per-slab exclusive prefix of row counts
#define WS_RLO   0
#define WS_P     (NSLAB * CUTN)
#define WS_WORDS (NSLAB * CUTN + NSLAB * (CUTN + 1))

// ---------- planning kernel: 1 block, no atomics, deterministic ----------
__global__ __launch_bounds__(256) void plan_kernel(
    const int* __restrict__ sizes, const int* __restrict__ offy,
    unsigned int* __restrict__ ws)
{
    __shared__ unsigned short s_rlo[NSLAB][CUTN];
    __shared__ unsigned short s_len[NSLAB][CUTN];
    const int t = threadIdx.x;
    for (int i = t; i < NSLAB * CUTN; i += 256) {
        (&s_rlo[0][0])[i] = 0;
        (&s_len[0][0])[i] = 0;
    }
    __syncthreads();
    if (t < CUTN) {
        // EXACTLY the same y0 formula as the main kernel.
        const float scale = (float)sizes[t] * (1.0f / (float)CUT_SIZE);
        const float oyf   = (float)offy[t];
        int cur_slab = -1, cur_start = 0;
        for (int r = 0; r < CUT_SIZE; ++r) {
            float fy = fmaf((float)r + 0.5f, scale, oyf - 0.5f);
            fy = fminf(fmaxf(fy, 0.0f), (float)(SIDE - 1));
            const int s = ((int)fy) >> 7;          // y0 monotone in r -> contiguous runs
            if (s != cur_slab) {
                if (cur_slab >= 0) s_len[cur_slab][t] = (unsigned short)(r - cur_start);
                s_rlo[s][t] = (unsigned short)r;
                cur_slab = s; cur_start = r;
            }
        }
        s_len[cur_slab][t] = (unsigned short)(CUT_SIZE - cur_start);
    }
    __syncthreads();
    if (t < NSLAB) {                               // tiny serial prefix per slab
        unsigned int run = 0;
        for (int n = 0; n < CUTN; ++n) {
            ws[WS_P + t * (CUTN + 1) + n] = run;
            run += s_len[t][n];
        }
        ws[WS_P + t * (CUTN + 1) + CUTN] = run;    // T(s)
    }
    for (int i = t; i < NSLAB * CUTN; i += 256)
        ws[WS_RLO + i] = (&s_rlo[0][0])[i];
}

// ---------- main kernel: one wave per output row, slab-local reads ----------
__global__ __launch_bounds__(256) void cutout_slab_kernel(
    const float* __restrict__ img,     // [3, 1024, 1024]
    const int* __restrict__ sizes,
    const int* __restrict__ offy,
    const int* __restrict__ offx,
    const unsigned int* __restrict__ ws,
    float* __restrict__ out)           // [128, 3, 224, 224]
{
    __shared__ float lds[4][LDSW];
    const int s    = blockIdx.x & 7;               // slab == XCD (all blocks co-resident)
    const int w    = threadIdx.x >> 6;             // wave 0..3
    const int lane = threadIdx.x & 63;
    const int q    = (blockIdx.x >> 3) * 4 + w;    // wave slot 0..895 within slab

    const unsigned int* __restrict__ P   = ws + WS_P + s * (CUTN + 1);
    const unsigned int* __restrict__ RLO = ws + WS_RLO + s * CUTN;
    const unsigned int T = P[CUTN];
    float* __restrict__ l = lds[w];

    for (unsigned int i = q; i < T; i += 896) {
        // find n with P[n] <= i < P[n+1] (7-step binary search, L1-hot)
        int lo = 0, hi = CUTN;
        while (hi - lo > 1) {
            const int mid = (lo + hi) >> 1;
            if (P[mid] <= i) lo = mid; else hi = mid;
        }
        const int n = lo;
        const int y = (int)RLO[n] + (int)(i - P[n]);   // output row of cutout n

        const float scale = (float)sizes[n] * (1.0f / (float)CUT_SIZE);
        const float oy = (float)offy[n];
        const float ox = (float)offx[n];

        float fy = fmaf((float)y + 0.5f, scale, oy - 0.5f);
        fy = fminf(fmaxf(fy, 0.0f), (float)(SIDE - 1));
        const int   y0 = (int)fy;                      // in slab s by construction
        const int   y1 = min(y0 + 1, SIDE - 1);
        const float wy  = fy - (float)y0;
        const float wy0 = 1.0f - wy;

        float fx0 = fmaf(0.5f, scale, ox - 0.5f);
        fx0 = fminf(fmaxf(fx0, 0.0f), (float)(SIDE - 1));
        float fxl = fmaf((float)CUT_SIZE - 0.5f, scale, ox - 0.5f);
        fxl = fminf(fmaxf(fxl, 0.0f), (float)(SIDE - 1));
        const int xb    = (int)fx0;
        const int xe    = min((int)fxl + 1, SIDE - 1);
        const int xb4   = xb & ~3;                     // 16B-aligned base
        const int ilast = xe - xb4;
        const int nf4   = (ilast >> 2) + 1;            // wave-uniform

        int   i0r[4], i1r[4];
        float wxr[4], wx0r[4];
#pragma unroll
        for (int it = 0; it < 4; ++it) {
            const int p = min(lane + it * 64, CUT_SIZE - 1);
            float fx = fmaf((float)p + 0.5f, scale, ox - 0.5f);
            fx = fminf(fmaxf(fx, 0.0f), (float)(SIDE - 1));
            const float fl = fx - (float)xb4;
            const int   i0 = (int)fl;
            i0r[it]  = i0;
            i1r[it]  = min(i0 + 1, ilast);
            wxr[it]  = fl - (float)i0;
            wx0r[it] = 1.0f - wxr[it];
        }

        const int r0off = y0 * SIDE + xb4;
        const int r1off = y1 * SIDE + xb4;
        const size_t obase0 = (((size_t)n * 3) * CUT_SIZE + y) * CUT_SIZE;

        for (int c = 0; c < 3; ++c) {
            const float* __restrict__ ch = img + (size_t)c * (SIDE * SIDE);
            const float4* __restrict__ rp0 = reinterpret_cast<const float4*>(ch + r0off);
            const float4* __restrict__ rp1 = reinterpret_cast<const float4*>(ch + r1off);
            // stage: load 2 rows (L2-hit: slab resident on this XCD), y-lerp, write LDS
            for (int k = lane; k < nf4; k += 64) {
                const float4 a = rp0[k];
                const float4 b = rp1[k];
                float4 r;
                r.x = a.x * wy0 + b.x * wy;
                r.y = a.y * wy0 + b.y * wy;
                r.z = a.z * wy0 + b.z * wy;
                r.w = a.w * wy0 + b.w * wy;
                *reinterpret_cast<float4*>(l + 4 * k) = r;
            }
            asm volatile("s_waitcnt lgkmcnt(0)" ::: "memory");  // wave-private LDS

            const size_t obase = obase0 + (size_t)c * (CUT_SIZE * CUT_SIZE);
#pragma unroll
            for (int it = 0; it < 4; ++it) {
                const int p = lane + it * 64;
                if (p < CUT_SIZE) {
                    const float a = l[i0r[it]];
                    const float b = l[i1r[it]];
                    float v = a * wx0r[it] + b * wxr[it];
                    v = fminf(fmaxf(v, 0.0f), 1.0f);
                    out[obase + p] = v;
                }
            }
            asm volatile("" ::: "memory");  // next ds_write must not pass these reads
        }
    }
}

// ---------- round-3 fallback (used only if ws_size is too small) ----------
__global__ __launch_bounds__(128) void make_cutouts_fallback(
    const float* __restrict__ img, const int* __restrict__ sizes,
    const int* __restrict__ offy, const int* __restrict__ offx,
    float* __restrict__ out)
{
    __shared__ float lds[2][LDSW];
    const int n    = blockIdx.y;
    const int w    = threadIdx.x >> 6;
    const int lane = threadIdx.x & 63;
    const int y    = blockIdx.x * 2 + w;

    const float scale = (float)sizes[n] * (1.0f / (float)CUT_SIZE);
    const float oy = (float)offy[n];
    const float ox = (float)offx[n];
    float fy = fmaf((float)y + 0.5f, scale, oy - 0.5f);
    fy = fminf(fmaxf(fy, 0.0f), (float)(SIDE - 1));
    const int   y0 = (int)fy;
    const int   y1 = min(y0 + 1, SIDE - 1);
    const float wy  = fy - (float)y0;
    const float wy0 = 1.0f - wy;
    float fx0 = fmaf(0.5f, scale, ox - 0.5f);
    fx0 = fminf(fmaxf(fx0, 0.0f), (float)(SIDE - 1));
    float fxl = fmaf((float)CUT_SIZE - 0.5f, scale, ox - 0.5f);
    fxl = fminf(fmaxf(fxl, 0.0f), (float)(SIDE - 1));
    const int xb = (int)fx0, xe = min((int)fxl + 1, SIDE - 1);
    const int xb4 = xb & ~3, ilast = xe - xb4, nf4 = (ilast >> 2) + 1;
    int i0r[4], i1r[4]; float wxr[4], wx0r[4];
#pragma unroll
    for (int it = 0; it < 4; ++it) {
        const int p = min(lane + it * 64, CUT_SIZE - 1);
        float fx = fmaf((float)p + 0.5f, scale, ox - 0.5f);
        fx = fminf(fmaxf(fx, 0.0f), (float)(SIDE - 1));
        const float fl = fx - (float)xb4;
        const int i0 = (int)fl;
        i0r[it] = i0; i1r[it] = min(i0 + 1, ilast);
        wxr[it] = fl - (float)i0; wx0r[it] = 1.0f - wxr[it];
    }
    const int r0off = y0 * SIDE + xb4, r1off = y1 * SIDE + xb4;
    float* __restrict__ l = lds[w];
    const size_t obase0 = (((size_t)n * 3) * CUT_SIZE + y) * CUT_SIZE;
    for (int c = 0; c < 3; ++c) {
        const float* __restrict__ ch = img + (size_t)c * (SIDE * SIDE);
        const float4* __restrict__ rp0 = reinterpret_cast<const float4*>(ch + r0off);
        const float4* __restrict__ rp1 = reinterpret_cast<const float4*>(ch + r1off);
        for (int k = lane; k < nf4; k += 64) {
            const float4 a = rp0[k]; const float4 b = rp1[k];
            float4 r;
            r.x = a.x * wy0 + b.x * wy; r.y = a.y * wy0 + b.y * wy;
            r.z = a.z * wy0 + b.z * wy; r.w = a.w * wy0 + b.w * wy;
            *reinterpret_cast<float4*>(l + 4 * k) = r;
        }
        asm volatile("s_waitcnt lgkmcnt(0)" ::: "memory");
        const size_t obase = obase0 + (size_t)c * (CUT_SIZE * CUT_SIZE);
#pragma unroll
        for (int it = 0; it < 4; ++it) {
            const int p = lane + it * 64;
            if (p < CUT_SIZE) {
                float v = l[i0r[it]] * wx0r[it] + l[i1r[it]] * wxr[it];
                v = fminf(fmaxf(v, 0.0f), 1.0f);
                out[obase + p] = v;
            }
        }
        asm volatile("" ::: "memory");
    }
}

extern "C" void kernel_launch(void* const* d_in, const int* in_sizes, int n_in,
                              void* d_out, int out_size, void* d_ws, size_t ws_size,
                              hipStream_t stream) {
    const float* img   = (const float*)d_in[0];
    const int*   sizes = (const int*)d_in[1];
    const int*   offy  = (const int*)d_in[2];
    const int*   offx  = (const int*)d_in[3];
    float*       out   = (float*)d_out;

    if (ws_size >= (size_t)WS_WORDS * 4) {
        unsigned int* ws = (unsigned int*)d_ws;
        plan_kernel<<<1, 256, 0, stream>>>(sizes, offy, ws);
        // 1792 blocks, 16.5 KB LDS -> 9 blocks/CU: entire grid co-resident,
        // so initial round-robin dispatch pins slab s = bid&7 to XCD s.
        cutout_slab_kernel<<<NSLAB * 224, 256, 0, stream>>>(img, sizes, offy, offx, ws, out);
    } else {
        make_cutouts_fallback<<<dim3(CUT_SIZE / 2, CUTN), 128, 0, stream>>>(
            img, sizes, offy, offx, out);
    }
}

// Round 7
// 50.394 us; speedup vs baseline: 1.6102x; 1.6102x over previous
//
#include <hip/hip_runtime.h>
#include <hip/hip_fp16.h>

#define CUT_SIZE 224
#define SIDE 1024
#define CUTN 128
#define NSLAB 8            // slab s -> XCD s via bid&7 (co-resident grid)
#define LDSW2 1032         // halves per channel row; max index used = ilast+1 <= 1024
#define SLAB_BLOCKS 192    // grid = 8*192 = 1536 blocks = 6/CU @ 24.8 KB LDS (all resident)
#define SLAB_WSLOTS (SLAB_BLOCKS * 4)

// d_ws layout (uint32 words):
//   RLO[NSLAB][CUTN]    : first output row of cutout n whose y0 falls in slab s
//   P[NSLAB][CUTN+1]    : per-slab exclusive prefix of run lengths
#define WS_RLO   0
#define WS_P     (NSLAB * CUTN)
#define WS_WORDS (NSLAB * CUTN + NSLAB * (CUTN + 1))

// ---------- plan: equal-task-count slab boundaries, closed-form counts ----------
// count_n(Y) = #{r in [0,224): y0(r) < Y} = clamp(ceil((Y+0.5-oy)/scale - 0.5), 0, 224)
// (scale >= 1 always; same expression used for CDF and runs -> exact partition)
__global__ __launch_bounds__(256) void plan_kernel(
    const int* __restrict__ sizes, const int* __restrict__ offy,
    unsigned int* __restrict__ ws)
{
    __shared__ float s_inv[CUTN], s_oy[CUTN];
    __shared__ int cdf[SIDE + 1];
    __shared__ int qb[NSLAB + 1];
    __shared__ unsigned short slen[NSLAB][CUTN];
    const int t = threadIdx.x;

    if (t < CUTN) {
        const float scale = (float)sizes[t] * (1.0f / (float)CUT_SIZE);
        s_inv[t] = 1.0f / scale;
        s_oy[t]  = (float)offy[t];
    }
    __syncthreads();

    for (int Y = t; Y <= SIDE; Y += 256) {
        int c = 0;
        for (int n = 0; n < CUTN; ++n) {
            const float thr = ((float)Y + 0.5f - s_oy[n]) * s_inv[n] - 0.5f;
            c += min(CUT_SIZE, max(0, (int)ceilf(thr)));
        }
        cdf[Y] = c;
    }
    __syncthreads();

    if (t >= 1 && t < NSLAB) {          // q[t] = min Y with cdf[Y] >= t*Ttot/8
        const int target = t * (CUTN * CUT_SIZE / NSLAB);
        int lo = 0, hi = SIDE;
        while (hi - lo > 1) { const int m = (lo + hi) >> 1; if (cdf[m] >= target) hi = m; else lo = m; }
        qb[t] = hi;
    }
    if (t == 0) { qb[0] = 0; qb[NSLAB] = SIDE; }
    __syncthreads();

    for (int idx = t; idx < NSLAB * CUTN; idx += 256) {
        const int s = idx >> 7, n = idx & (CUTN - 1);
        int rlo, rhi;
        {
            const int Y = qb[s];
            if (Y <= 0) rlo = 0;
            else { const float thr = ((float)Y + 0.5f - s_oy[n]) * s_inv[n] - 0.5f;
                   rlo = min(CUT_SIZE, max(0, (int)ceilf(thr))); }
        }
        {
            const int Y = qb[s + 1];
            if (Y >= SIDE) rhi = CUT_SIZE;
            else { const float thr = ((float)Y + 0.5f - s_oy[n]) * s_inv[n] - 0.5f;
                   rhi = min(CUT_SIZE, max(0, (int)ceilf(thr))); }
        }
        ws[WS_RLO + idx] = (unsigned int)rlo;
        slen[s][n] = (unsigned short)(rhi - rlo);
    }
    __syncthreads();

    if (t < NSLAB) {
        unsigned int run = 0;
        for (int n = 0; n < CUTN; ++n) { ws[WS_P + t * (CUTN + 1) + n] = run; run += slen[t][n]; }
        ws[WS_P + t * (CUTN + 1) + CUTN] = run;
    }
}

// ---------- main: one wave per row-task, 3 channels batched, fp16 LDS ----------
__global__ __launch_bounds__(256) void cutout_slab_kernel(
    const float* __restrict__ img,     // [3, 1024, 1024]
    const int* __restrict__ sizes,
    const int* __restrict__ offy,
    const int* __restrict__ offx,
    const unsigned int* __restrict__ ws,
    float* __restrict__ out)           // [128, 3, 224, 224]
{
    __shared__ __half lds[4][3][LDSW2];   // 24.8 KB: wave-private 3-channel rows
    const int s    = blockIdx.x & 7;      // slab == XCD
    const int w    = threadIdx.x >> 6;
    const int lane = threadIdx.x & 63;
    const int q    = (blockIdx.x >> 3) * 4 + w;   // wave slot within slab

    const unsigned int* __restrict__ P   = ws + WS_P + s * (CUTN + 1);
    const unsigned int* __restrict__ RLO = ws + WS_RLO + s * CUTN;
    const unsigned int T = P[CUTN];
    __half* __restrict__ l0 = &lds[w][0][0];
    __half* __restrict__ l1 = &lds[w][1][0];
    __half* __restrict__ l2 = &lds[w][2][0];

    for (unsigned int i = q; i < T; i += SLAB_WSLOTS) {
        int lo = 0, hi = CUTN;                      // P[n] <= i < P[n+1]
        while (hi - lo > 1) { const int m = (lo + hi) >> 1; if (P[m] <= i) lo = m; else hi = m; }
        const int n = lo;
        const int y = (int)RLO[n] + (int)(i - P[n]);

        const float scale = (float)sizes[n] * (1.0f / (float)CUT_SIZE);
        const float oy = (float)offy[n];
        const float ox = (float)offx[n];

        float fy = fmaf((float)y + 0.5f, scale, oy - 0.5f);
        fy = fminf(fmaxf(fy, 0.0f), (float)(SIDE - 1));
        const int   y0 = (int)fy;
        const int   y1 = min(y0 + 1, SIDE - 1);
        const float wy  = fy - (float)y0;
        const float wy0 = 1.0f - wy;

        float fx0 = fmaf(0.5f, scale, ox - 0.5f);
        fx0 = fminf(fmaxf(fx0, 0.0f), (float)(SIDE - 1));
        float fxl = fmaf((float)CUT_SIZE - 0.5f, scale, ox - 0.5f);
        fxl = fminf(fmaxf(fxl, 0.0f), (float)(SIDE - 1));
        const int xb    = (int)fx0;
        const int xe    = min((int)fxl + 1, SIDE - 1);
        const int xb4   = xb & ~3;
        const int ilast = xe - xb4;
        const int nf4   = (ilast >> 2) + 1;         // wave-uniform

        int   i0r[4];
        float wxr[4], wx0r[4];
#pragma unroll
        for (int it = 0; it < 4; ++it) {
            const int p = min(lane + it * 64, CUT_SIZE - 1);
            float fx = fmaf((float)p + 0.5f, scale, ox - 0.5f);
            fx = fminf(fmaxf(fx, 0.0f), (float)(SIDE - 1));
            const float fl = fx - (float)xb4;
            const int   i0 = (int)fl;
            i0r[it]  = i0;                          // i1 = i0+1 (pad below)
            wxr[it]  = fl - (float)i0;
            wx0r[it] = 1.0f - wxr[it];
        }

        const size_t cstride = (size_t)SIDE * SIDE;
        const float* b0 = img + (size_t)y0 * SIDE + xb4;
        const float* b1 = img + (size_t)y1 * SIDE + xb4;
        const float4* __restrict__ rp0 = reinterpret_cast<const float4*>(b0);
        const float4* __restrict__ rq0 = reinterpret_cast<const float4*>(b1);
        const float4* __restrict__ rp1 = reinterpret_cast<const float4*>(b0 + cstride);
        const float4* __restrict__ rq1 = reinterpret_cast<const float4*>(b1 + cstride);
        const float4* __restrict__ rp2 = reinterpret_cast<const float4*>(b0 + 2 * cstride);
        const float4* __restrict__ rq2 = reinterpret_cast<const float4*>(b1 + 2 * cstride);

        // Stage all 3 channels: 6 independent L2-local float4 loads per iter.
        // Last float4 base col = xb4+4(nf4-1) <= xe <= 1023, 4-aligned: never OOB.
        for (int k = lane; k < nf4; k += 64) {
            const float4 a0 = rp0[k], c0 = rq0[k];
            const float4 a1 = rp1[k], c1 = rq1[k];
            const float4 a2 = rp2[k], c2 = rq2[k];
            union { __half2 h[2]; uint2 u; } pk;
            pk.h[0] = __floats2half2_rn(a0.x * wy0 + c0.x * wy, a0.y * wy0 + c0.y * wy);
            pk.h[1] = __floats2half2_rn(a0.z * wy0 + c0.z * wy, a0.w * wy0 + c0.w * wy);
            *reinterpret_cast<uint2*>(l0 + 4 * k) = pk.u;
            pk.h[0] = __floats2half2_rn(a1.x * wy0 + c1.x * wy, a1.y * wy0 + c1.y * wy);
            pk.h[1] = __floats2half2_rn(a1.z * wy0 + c1.z * wy, a1.w * wy0 + c1.w * wy);
            *reinterpret_cast<uint2*>(l1 + 4 * k) = pk.u;
            pk.h[0] = __floats2half2_rn(a2.x * wy0 + c2.x * wy, a2.y * wy0 + c2.y * wy);
            pk.h[1] = __floats2half2_rn(a2.z * wy0 + c2.z * wy, a2.w * wy0 + c2.w * wy);
            *reinterpret_cast<uint2*>(l2 + 4 * k) = pk.u;
        }
        // Pad zero at ilast+1 (read only when wx==0; avoids stale-LDS NaN*0).
        if (lane < 3) lds[w][lane][ilast + 1] = __float2half(0.0f);
        // Wave-private LDS: one drain per task; "memory" stops reordering.
        asm volatile("s_waitcnt lgkmcnt(0)" ::: "memory");

        const size_t obase0 = (((size_t)n * 3) * CUT_SIZE + y) * CUT_SIZE;
#pragma unroll
        for (int c = 0; c < 3; ++c) {
            const __half* __restrict__ lc = &lds[w][c][0];
            const size_t obase = obase0 + (size_t)c * (CUT_SIZE * CUT_SIZE);
#pragma unroll
            for (int it = 0; it < 4; ++it) {
                const int p = lane + it * 64;
                if (p < CUT_SIZE) {
                    const int i0 = i0r[it];
                    const float v0 = __half2float(lc[i0]);
                    const float v1 = __half2float(lc[i0 + 1]);
                    float v = v0 * wx0r[it] + v1 * wxr[it];
                    v = fminf(fmaxf(v, 0.0f), 1.0f);
                    out[obase + p] = v;
                }
            }
        }
        // Next task's ds_writes must not be hoisted past these ds_reads.
        asm volatile("" ::: "memory");
    }
}

// ---------- fallback (only if ws too small) ----------
__global__ __launch_bounds__(128) void make_cutouts_fallback(
    const float* __restrict__ img, const int* __restrict__ sizes,
    const int* __restrict__ offy, const int* __restrict__ offx,
    float* __restrict__ out)
{
    __shared__ float lds[2][1032];
    const int n    = blockIdx.y;
    const int w    = threadIdx.x >> 6;
    const int lane = threadIdx.x & 63;
    const int y    = blockIdx.x * 2 + w;
    const float scale = (float)sizes[n] * (1.0f / (float)CUT_SIZE);
    const float oy = (float)offy[n];
    const float ox = (float)offx[n];
    float fy = fmaf((float)y + 0.5f, scale, oy - 0.5f);
    fy = fminf(fmaxf(fy, 0.0f), (float)(SIDE - 1));
    const int y0 = (int)fy, y1 = min(y0 + 1, SIDE - 1);
    const float wy = fy - (float)y0, wy0 = 1.0f - wy;
    float fx0 = fmaf(0.5f, scale, ox - 0.5f);
    fx0 = fminf(fmaxf(fx0, 0.0f), (float)(SIDE - 1));
    float fxl = fmaf((float)CUT_SIZE - 0.5f, scale, ox - 0.5f);
    fxl = fminf(fmaxf(fxl, 0.0f), (float)(SIDE - 1));
    const int xb = (int)fx0, xe = min((int)fxl + 1, SIDE - 1);
    const int xb4 = xb & ~3, ilast = xe - xb4, nf4 = (ilast >> 2) + 1;
    int i0r[4], i1r[4]; float wxr[4], wx0r[4];
#pragma unroll
    for (int it = 0; it < 4; ++it) {
        const int p = min(lane + it * 64, CUT_SIZE - 1);
        float fx = fmaf((float)p + 0.5f, scale, ox - 0.5f);
        fx = fminf(fmaxf(fx, 0.0f), (float)(SIDE - 1));
        const float fl = fx - (float)xb4;
        const int i0 = (int)fl;
        i0r[it] = i0; i1r[it] = min(i0 + 1, ilast);
        wxr[it] = fl - (float)i0; wx0r[it] = 1.0f - wxr[it];
    }
    const int r0off = y0 * SIDE + xb4, r1off = y1 * SIDE + xb4;
    float* __restrict__ l = lds[w];
    const size_t obase0 = (((size_t)n * 3) * CUT_SIZE + y) * CUT_SIZE;
    for (int c = 0; c < 3; ++c) {
        const float* __restrict__ ch = img + (size_t)c * (SIDE * SIDE);
        const float4* __restrict__ rp0 = reinterpret_cast<const float4*>(ch + r0off);
        const float4* __restrict__ rp1 = reinterpret_cast<const float4*>(ch + r1off);
        for (int k = lane; k < nf4; k += 64) {
            const float4 a = rp0[k]; const float4 b = rp1[k];
            float4 r;
            r.x = a.x * wy0 + b.x * wy; r.y = a.y * wy0 + b.y * wy;
            r.z = a.z * wy0 + b.z * wy; r.w = a.w * wy0 + b.w * wy;
            *reinterpret_cast<float4*>(l + 4 * k) = r;
        }
        asm volatile("s_waitcnt lgkmcnt(0)" ::: "memory");
        const size_t obase = obase0 + (size_t)c * (CUT_SIZE * CUT_SIZE);
#pragma unroll
        for (int it = 0; it < 4; ++it) {
            const int p = lane + it * 64;
            if (p < CUT_SIZE) {
                float v = l[i0r[it]] * wx0r[it] + l[i1r[it]] * wxr[it];
                v = fminf(fmaxf(v, 0.0f), 1.0f);
                out[obase + p] = v;
            }
        }
        asm volatile("" ::: "memory");
    }
}

extern "C" void kernel_launch(void* const* d_in, const int* in_sizes, int n_in,
                              void* d_out, int out_size, void* d_ws, size_t ws_size,
                              hipStream_t stream) {
    const float* img   = (const float*)d_in[0];
    const int*   sizes = (const int*)d_in[1];
    const int*   offy  = (const int*)d_in[2];
    const int*   offx  = (const int*)d_in[3];
    float*       out   = (float*)d_out;

    if (ws_size >= (size_t)WS_WORDS * 4) {
        unsigned int* ws = (unsigned int*)d_ws;
        plan_kernel<<<1, 256, 0, stream>>>(sizes, offy, ws);
        cutout_slab_kernel<<<NSLAB * SLAB_BLOCKS, 256, 0, stream>>>(
            img, sizes, offy, offx, ws, out);
    } else {
        make_cutouts_fallback<<<dim3(CUT_SIZE / 2, CUTN), 128, 0, stream>>>(
            img, sizes, offy, offx, out);
    }
}